// Round 6
// baseline (65.724 us; speedup 1.0000x reference)
//
#include <hip/hip_runtime.h>
#include <hip/hip_bf16.h>

typedef float f32x4 __attribute__((ext_vector_type(4)));
typedef __bf16 bf16x8 __attribute__((ext_vector_type(8)));

#define AS1 __attribute__((address_space(1)))
#define AS3 __attribute__((address_space(3)))

static constexpr int BB = 32;      // batch
static constexpr int DM = 2560;    // d_model
static constexpr int DI = 5120;    // d_inner
static constexpr int NS = 16;      // ssm state N
static constexpr int RK = 160;     // dt_rank
static constexpr int NJ = 192;     // dt_rank + 2N

__device__ __forceinline__ float sigmoidf_(float x) { return 1.f / (1.f + __expf(-x)); }
__device__ __forceinline__ float softplusf_(float x) {
    return (x > 15.f) ? x : log1pf(__expf(x));
}

__device__ __forceinline__ bf16x8 cvt8(f32x4 a, f32x4 b) {
    bf16x8 r;
    r[0] = (__bf16)a[0]; r[1] = (__bf16)a[1]; r[2] = (__bf16)a[2]; r[3] = (__bf16)a[3];
    r[4] = (__bf16)b[0]; r[5] = (__bf16)b[1]; r[6] = (__bf16)b[2]; r[7] = (__bf16)b[3];
    return r;
}

#define WAITN(N) do { asm volatile("s_waitcnt vmcnt(" #N ")" ::: "memory"); \
                      __builtin_amdgcn_sched_barrier(0); } while (0)

// ---------------------------------------------------------------------------
// Big-tile skinny GEMM: 128 d x 32 b tile, BK=32, 4 waves (each 32d x 32b,
// 4 MFMA/kstep). W + X staged via global_load_lds (1KB/instr, 5 instr/wave/
// kstep), double-buffered, counted vmcnt(5), raw barriers. LDS rows = 32
// floats = 8 x 16B chunks; slot (row,c) holds global chunk c^(row&7) via
// pre-swizzled per-lane global source (m173); frag ds_read_b128 unswizzles
// with the same XOR -> 8 lanes/bank-quad uniform (conflict-free).
// Split-K partials to disjoint buffers (C + s*cstride); consumer reduces.
// ---------------------------------------------------------------------------
__global__ __launch_bounds__(256) void gemm128(
    const float* __restrict__ W0, float* __restrict__ C0,
    const float* __restrict__ W1, float* __restrict__ C1,
    const float* __restrict__ X,
    int K, int ldc, int nm, int S, int ksteps, int cstride)
{
    __shared__ float Wb[2][128 * 32];
    __shared__ float Xb[2][32 * 32];

    int bid = blockIdx.x;
    int m = bid % nm;
    int rest = bid / nm;
    int s = rest % S;
    int mat = rest / S;
    const float* W = mat ? W1 : W0;
    float* C = (mat ? C1 : C0) + (size_t)s * cstride;

    int d0 = m * 128;
    int k0 = s * (K / S);

    int t = threadIdx.x;
    int l = t & 63;
    int w = t >> 6;             // wave 0..3

    // ---- staging (per wave: 4 W instrs = rows 32w..32w+31, 1 X instr = rows 8w..8w+7)
    int rr = l >> 3;            // row within 8-row group (0..7)
    int ch = (l & 7) ^ rr;      // pre-swizzled 16B chunk (row&7 == rr for 8-aligned bases)
    const float* wp0 = W + (size_t)(d0 + 32 * w +  0 + rr) * K + k0 + ch * 4;
    const float* wp1 = W + (size_t)(d0 + 32 * w +  8 + rr) * K + k0 + ch * 4;
    const float* wp2 = W + (size_t)(d0 + 32 * w + 16 + rr) * K + k0 + ch * 4;
    const float* wp3 = W + (size_t)(d0 + 32 * w + 24 + rr) * K + k0 + ch * 4;
    const float* xp  = X + (size_t)(8 * w + rr) * K + k0 + ch * 4;
    int wd0 = (32 * w +  0) * 32;
    int wd1 = (32 * w +  8) * 32;
    int wd2 = (32 * w + 16) * 32;
    int wd3 = (32 * w + 24) * 32;
    int xd  = (8 * w) * 32;

#define STAGE(pb) do {                                                                  \
        __builtin_amdgcn_global_load_lds((const AS1 void*)wp0, (AS3 void*)&Wb[pb][wd0], 16, 0, 0); \
        __builtin_amdgcn_global_load_lds((const AS1 void*)wp1, (AS3 void*)&Wb[pb][wd1], 16, 0, 0); \
        __builtin_amdgcn_global_load_lds((const AS1 void*)wp2, (AS3 void*)&Wb[pb][wd2], 16, 0, 0); \
        __builtin_amdgcn_global_load_lds((const AS1 void*)wp3, (AS3 void*)&Wb[pb][wd3], 16, 0, 0); \
        __builtin_amdgcn_global_load_lds((const AS1 void*)xp,  (AS3 void*)&Xb[pb][xd],  16, 0, 0); \
        wp0 += 32; wp1 += 32; wp2 += 32; wp3 += 32; xp += 32;                           \
    } while (0)

    // ---- fragment read offsets (BK=32: frag = chunks 2j,2j+1, j = l>>4)
    int r16 = l & 15;
    int j2 = (l >> 4) * 2;
    int ar0 = 32 * w + r16;          // A-frag m=0 row
    int ar1 = 32 * w + 16 + r16;     // A-frag m=1 row
    int br0 = r16;                   // B-frag n=0 row
    int br1 = 16 + r16;              // B-frag n=1 row
    int a00 = ar0 * 32 + ((j2    ) ^ (ar0 & 7)) * 4;
    int a01 = ar0 * 32 + ((j2 + 1) ^ (ar0 & 7)) * 4;
    int a10 = ar1 * 32 + ((j2    ) ^ (ar1 & 7)) * 4;
    int a11 = ar1 * 32 + ((j2 + 1) ^ (ar1 & 7)) * 4;
    int b00 = br0 * 32 + ((j2    ) ^ (br0 & 7)) * 4;
    int b01 = br0 * 32 + ((j2 + 1) ^ (br0 & 7)) * 4;
    int b10 = br1 * 32 + ((j2    ) ^ (br1 & 7)) * 4;
    int b11 = br1 * 32 + ((j2 + 1) ^ (br1 & 7)) * 4;

    STAGE(0);
    STAGE(1);

    f32x4 acc00 = {0.f, 0.f, 0.f, 0.f}, acc01 = {0.f, 0.f, 0.f, 0.f};
    f32x4 acc10 = {0.f, 0.f, 0.f, 0.f}, acc11 = {0.f, 0.f, 0.f, 0.f};

    for (int it = 0; it < ksteps; ++it) {
        int c = it & 1;
        if (it < ksteps - 1) WAITN(5); else WAITN(0);
        __builtin_amdgcn_s_barrier();

        f32x4 wa0 = *(const f32x4*)&Wb[c][a00];
        f32x4 wa1 = *(const f32x4*)&Wb[c][a01];
        f32x4 wb0 = *(const f32x4*)&Wb[c][a10];
        f32x4 wb1 = *(const f32x4*)&Wb[c][a11];
        f32x4 xa0 = *(const f32x4*)&Xb[c][b00];
        f32x4 xa1 = *(const f32x4*)&Xb[c][b01];
        f32x4 xb0 = *(const f32x4*)&Xb[c][b10];
        f32x4 xb1 = *(const f32x4*)&Xb[c][b11];

        bf16x8 A0 = cvt8(wa0, wa1);
        bf16x8 A1 = cvt8(wb0, wb1);
        bf16x8 B0 = cvt8(xa0, xa1);
        bf16x8 B1 = cvt8(xb0, xb1);
        acc00 = __builtin_amdgcn_mfma_f32_16x16x32_bf16(A0, B0, acc00, 0, 0, 0);
        acc01 = __builtin_amdgcn_mfma_f32_16x16x32_bf16(A0, B1, acc01, 0, 0, 0);
        acc10 = __builtin_amdgcn_mfma_f32_16x16x32_bf16(A1, B0, acc10, 0, 0, 0);
        acc11 = __builtin_amdgcn_mfma_f32_16x16x32_bf16(A1, B1, acc11, 0, 0, 0);

        __builtin_amdgcn_s_barrier();
        if (it + 2 < ksteps) STAGE(c);
    }
#undef STAGE

    // C/D: col(batch) = l&15, row(d) = (l>>4)*4 + reg
    int q4 = (l >> 4) * 4;
    *(f32x4*)&C[(size_t)(br0) * ldc + d0 + 32 * w      + q4] = acc00;
    *(f32x4*)&C[(size_t)(br1) * ldc + d0 + 32 * w      + q4] = acc01;
    *(f32x4*)&C[(size_t)(br0) * ldc + d0 + 32 * w + 16 + q4] = acc10;
    *(f32x4*)&C[(size_t)(br1) * ldc + d0 + 32 * w + 16 + q4] = acc11;
}

// ---------------------------------------------------------------------------
// Small-tile GEMM (unchanged, proven): used for K2 only (output D=192).
// ---------------------------------------------------------------------------
__global__ __launch_bounds__(256) void gemm32(
    const float* __restrict__ W0, float* __restrict__ C0,
    const float* __restrict__ W1, float* __restrict__ C1,
    const float* __restrict__ X,
    int K, int ldc, int nm, int S, int ksteps, int cstride)
{
    __shared__ float Wb[2][32 * 64];
    __shared__ float Xb[2][32 * 64];

    int bid = blockIdx.x;
    int m = bid % nm;
    int rest = bid / nm;
    int s = rest % S;
    int mat = rest / S;
    const float* W = mat ? W1 : W0;
    float* C = (mat ? C1 : C0) + (size_t)s * cstride;

    int d0 = m * 32;
    int k0 = s * (K / S);

    int t  = threadIdx.x;
    int l  = t & 63;
    int wv = t >> 6;
    int lr = l >> 4;
    int lc = l & 15;

    int row0 = 8 * wv + lr;
    int row1 = row0 + 4;
    int ch0 = lc ^ (row0 & 7);
    int ch1 = lc ^ (row1 & 7);
    const float* ws0 = W + (size_t)(d0 + row0) * K + k0 + ch0 * 4;
    const float* ws1 = W + (size_t)(d0 + row1) * K + k0 + ch1 * 4;
    const float* xs0 = X + (size_t)row0 * K + k0 + ch0 * 4;
    const float* xs1 = X + (size_t)row1 * K + k0 + ch1 * 4;
    int R0 = 8 * wv * 64;
    int R1 = (8 * wv + 4) * 64;

#define STAGE(pb)  do {                                                              \
        __builtin_amdgcn_global_load_lds((const AS1 void*)ws0, (AS3 void*)&Wb[pb][R0], 16, 0, 0); \
        __builtin_amdgcn_global_load_lds((const AS1 void*)ws1, (AS3 void*)&Wb[pb][R1], 16, 0, 0); \
        __builtin_amdgcn_global_load_lds((const AS1 void*)xs0, (AS3 void*)&Xb[pb][R0], 16, 0, 0); \
        __builtin_amdgcn_global_load_lds((const AS1 void*)xs1, (AS3 void*)&Xb[pb][R1], 16, 0, 0); \
        ws0 += 64; ws1 += 64; xs0 += 64; xs1 += 64;                                  \
    } while (0)

    int mh = wv & 1, nh = wv >> 1;
    int r16 = l & 15;
    int arow = mh * 16 + r16;
    int brow = nh * 16 + r16;
    int c0 = (l >> 4) * 2;
    int wo0 = arow * 64 + ((c0    ) ^ (arow & 7)) * 4;
    int wo1 = arow * 64 + ((c0 + 1) ^ (arow & 7)) * 4;
    int wo2 = arow * 64 + ((c0 + 8) ^ (arow & 7)) * 4;
    int wo3 = arow * 64 + ((c0 + 9) ^ (arow & 7)) * 4;
    int xo0 = brow * 64 + ((c0    ) ^ (brow & 7)) * 4;
    int xo1 = brow * 64 + ((c0 + 1) ^ (brow & 7)) * 4;
    int xo2 = brow * 64 + ((c0 + 8) ^ (brow & 7)) * 4;
    int xo3 = brow * 64 + ((c0 + 9) ^ (brow & 7)) * 4;

    STAGE(0);
    STAGE(1);

    f32x4 acc = {0.f, 0.f, 0.f, 0.f};

    for (int it = 0; it < ksteps; ++it) {
        int c = it & 1;
        if (it < ksteps - 1) WAITN(4); else WAITN(0);
        __builtin_amdgcn_s_barrier();

        f32x4 a0 = *(const f32x4*)&Wb[c][wo0];
        f32x4 a1 = *(const f32x4*)&Wb[c][wo1];
        f32x4 a2 = *(const f32x4*)&Wb[c][wo2];
        f32x4 a3 = *(const f32x4*)&Wb[c][wo3];
        f32x4 b0 = *(const f32x4*)&Xb[c][xo0];
        f32x4 b1 = *(const f32x4*)&Xb[c][xo1];
        f32x4 b2 = *(const f32x4*)&Xb[c][xo2];
        f32x4 b3 = *(const f32x4*)&Xb[c][xo3];
        acc = __builtin_amdgcn_mfma_f32_16x16x32_bf16(cvt8(a0, a1), cvt8(b0, b1), acc, 0, 0, 0);
        acc = __builtin_amdgcn_mfma_f32_16x16x32_bf16(cvt8(a2, a3), cvt8(b2, b3), acc, 0, 0, 0);

        __builtin_amdgcn_s_barrier();
        if (it + 2 < ksteps) STAGE(c);
    }
#undef STAGE

    int b = brow;
    int dbase = d0 + mh * 16 + (l >> 4) * 4;
    *(f32x4*)&C[(size_t)b * ldc + dbase] = acc;
}

// ---------------------------------------------------------------------------
// Depthwise causal conv (k=4) + SiLU + reduce K1 split-K partials (S=8).
// ---------------------------------------------------------------------------
__global__ __launch_bounds__(256) void convk(
    const float* __restrict__ P_xs, const float* __restrict__ P_res,
    const float* __restrict__ conv_states,
    const float* __restrict__ conv_w, const float* __restrict__ conv_b,
    float* __restrict__ conv_bd, float* __restrict__ res_bd)
{
    const size_t BD = (size_t)BB * DI;
    int d = blockIdx.x * 256 + threadIdx.x;
    int b = blockIdx.y;
    size_t o = (size_t)b * DI + d;
    float xs = 0.f, rs = 0.f;
    #pragma unroll
    for (int j = 0; j < 8; ++j) {
        xs += P_xs[j * BD + o];
        rs += P_res[j * BD + o];
    }
    res_bd[o] = rs;
    float v = conv_states[(size_t)(1 * BB + b) * DI + d] * conv_w[0 * DI + d]
            + conv_states[(size_t)(2 * BB + b) * DI + d] * conv_w[1 * DI + d]
            + conv_states[(size_t)(3 * BB + b) * DI + d] * conv_w[2 * DI + d]
            + xs * conv_w[3 * DI + d] + conv_b[d];
    conv_bd[o] = v * sigmoidf_(v);
}

// ---------------------------------------------------------------------------
// Reduce K2 split-K partials.
// ---------------------------------------------------------------------------
__global__ __launch_bounds__(256) void redx(
    const float* __restrict__ p, float* __restrict__ o, int S)
{
    int i = blockIdx.x * 256 + threadIdx.x;
    float sum = 0.f;
    for (int s = 0; s < S; ++s) sum += p[(size_t)s * BB * NJ + i];
    o[i] = sum;
}

// ---------------------------------------------------------------------------
// Reduce K4 split-K partials (S=16) into d_out.
// ---------------------------------------------------------------------------
__global__ __launch_bounds__(256) void rout(
    const float* __restrict__ p, float* __restrict__ o)
{
    const int SZ = BB * DM;
    int i = blockIdx.x * 256 + threadIdx.x;
    float s = 0.f;
    #pragma unroll
    for (int j = 0; j < 16; ++j) s += p[(size_t)j * SZ + i];
    o[i] = s;
}

// ---------------------------------------------------------------------------
// dt GEMV: dt[b][d] = softplus(x_db[b,0:160] @ W_dt[d,:] + dt_bias[d]).
// ---------------------------------------------------------------------------
__global__ __launch_bounds__(256) void dtk(
    const float* __restrict__ x_db, const float* __restrict__ W_dt,
    const float* __restrict__ dt_bias, float* __restrict__ dt_bd)
{
    __shared__ float Wdt_s[8][164];
    __shared__ float xdb_s[BB][164];

    int t = threadIdx.x;
    int d0 = blockIdx.x * 8;

    for (int f = t; f < 8 * RK; f += 256) {
        Wdt_s[f / RK][f % RK] = W_dt[(size_t)d0 * RK + f];
    }
    for (int f = t; f < BB * RK; f += 256) {
        int b = f / RK, k = f % RK;
        xdb_s[b][k] = x_db[(size_t)b * NJ + k];
    }
    __syncthreads();

    int b  = t & 31;
    int dl = t >> 5;

    float acc = 0.f;
    #pragma unroll 8
    for (int k4 = 0; k4 < RK / 4; ++k4) {
        f32x4 wv = *(const f32x4*)&Wdt_s[dl][k4 * 4];
        f32x4 xv = *(const f32x4*)&xdb_s[b][k4 * 4];
        acc += wv[0] * xv[0] + wv[1] * xv[1] + wv[2] * xv[2] + wv[3] * xv[3];
    }

    int d = d0 + dl;
    dt_bd[(size_t)b * DI + d] = softplusf_(acc + dt_bias[d]);
}

// ---------------------------------------------------------------------------
// SSM recurrence + D skip + SiLU gate.  One thread per (b,d).
// ---------------------------------------------------------------------------
__global__ __launch_bounds__(256) void ssm2(
    const float* __restrict__ x_db, const float* __restrict__ dt_bd,
    const float* __restrict__ A_log, const float* __restrict__ Dv,
    const float* __restrict__ ssm_state, const float* __restrict__ conv_bd,
    const float* __restrict__ res_bd, float* __restrict__ g_bd)
{
    __shared__ float Bc[NS], Cc[NS];

    int t = threadIdx.x;
    int b = blockIdx.x / (DI / 256);
    int dblk = blockIdx.x % (DI / 256);
    int d = dblk * 256 + t;

    if (t < NS) Bc[t] = x_db[(size_t)b * NJ + RK + t];
    else if (t < 2 * NS) Cc[t - NS] = x_db[(size_t)b * NJ + RK + t];
    __syncthreads();

    size_t off = (size_t)b * DI + d;
    float dt = dt_bd[off];
    float cv = conv_bd[off];
    float rv = res_bd[off];
    float Dd = Dv[d];

    const f32x4* ap = (const f32x4*)(A_log + (size_t)d * NS);
    const f32x4* sp = (const f32x4*)(ssm_state + off * NS);

    float y = 0.f;
    #pragma unroll
    for (int q = 0; q < 4; ++q) {
        f32x4 al = ap[q];
        f32x4 sv = sp[q];
        #pragma unroll
        for (int j = 0; j < 4; ++j) {
            int n = q * 4 + j;
            float dA = __expf(-dt * __expf(al[j]));
            y += (sv[j] * dA + dt * Bc[n] * cv) * Cc[n];
        }
    }
    y += Dd * cv;
    g_bd[off] = y * (rv * sigmoidf_(rv));
}

// ---------------------------------------------------------------------------

extern "C" void kernel_launch(void* const* d_in, const int* in_sizes, int n_in,
                              void* d_out, int out_size, void* d_ws, size_t ws_size,
                              hipStream_t stream)
{
    const float* x           = (const float*)d_in[0];
    const float* conv_states = (const float*)d_in[1];
    const float* conv_w      = (const float*)d_in[2];
    const float* conv_b      = (const float*)d_in[3];
    const float* W_ssm_in    = (const float*)d_in[4];
    const float* W_mlp       = (const float*)d_in[5];
    const float* W_out       = (const float*)d_in[6];
    const float* W_x_proj    = (const float*)d_in[7];
    const float* W_dt        = (const float*)d_in[8];
    const float* dt_bias     = (const float*)d_in[9];
    const float* A_log       = (const float*)d_in[10];
    const float* Dv          = (const float*)d_in[11];
    const float* ssm_state   = (const float*)d_in[12];

    float* out = (float*)d_out;
    float* ws  = (float*)d_ws;

    const size_t BD = (size_t)BB * DI;          // 163840
    const int S1 = 8;                           // K1 split-K (gemm128)
    const int S2 = 20;                          // K2 split-K (gemm32)
    const int S4 = 16;                          // K4 split-K (gemm128)

    float* P_res   = ws;                        // S1*BD
    float* P_xs    = ws + S1 * BD;              // S1*BD
    float* conv_bd = ws + 2 * S1 * BD;
    float* res_bd  = conv_bd + BD;
    float* dt_bd   = res_bd + BD;
    float* x_db_p  = dt_bd + BD;                // S2 * 6144
    float* x_db    = x_db_p + (size_t)S2 * BB * NJ;
    float* g_bd    = P_res;                     // alias: P_res dead after convk
    float* outp    = P_xs;                      // alias: P_xs dead after convk (S4*BB*DM = 8*BD)

    // K1: res/xs partials (dual matrix): K=2560, tile 128d, S=8, BK=32 -> ksteps=10
    gemm128<<<dim3((DI / 128) * S1 * 2), 256, 0, stream>>>(
        W_mlp, P_res, W_ssm_in, P_xs, x, DM, DI, DI / 128, S1, (DM / S1) / 32, (int)BD);

    // conv + silu + reduce K1 partials
    convk<<<dim3(DI / 256, BB), 256, 0, stream>>>(
        P_xs, P_res, conv_states, conv_w, conv_b, conv_bd, res_bd);

    // K2: x_db partials = conv @ W_x_proj.T  (K=5120, S=20, ksteps=4, BK=64)
    gemm32<<<dim3(6 * S2), 256, 0, stream>>>(
        W_x_proj, x_db_p, W_x_proj, x_db_p, conv_bd, DI, NJ, 6, S2, (DI / S2) / 64, BB * NJ);

    // reduce x_db partials
    redx<<<dim3((BB * NJ) / 256), 256, 0, stream>>>(x_db_p, x_db, S2);

    // dt GEMV + softplus
    dtk<<<dim3(DI / 8), 256, 0, stream>>>(x_db, W_dt, dt_bias, dt_bd);

    // SSM recurrence + gate
    ssm2<<<dim3(BB * (DI / 256)), 256, 0, stream>>>(
        x_db, dt_bd, A_log, Dv, ssm_state, conv_bd, res_bd, g_bd);

    // K4: out partials = g @ W_out.T  (K=5120, tile 128d, S=16, BK=32 -> ksteps=10)
    gemm128<<<dim3((DM / 128) * S4), 256, 0, stream>>>(
        W_out, outp, W_out, outp, g_bd, DI, DM, DM / 128, S4, (DI / S4) / 32, BB * DM);

    // final reduce into d_out
    rout<<<dim3((BB * DM) / 256), 256, 0, stream>>>(outp, out);
}